// Round 1
// baseline (264.377 us; speedup 1.0000x reference)
//
#include <hip/hip_runtime.h>
#include <hip/hip_bf16.h>

// Problem constants (match reference setup_inputs()).
#define N 4096
#define D 256
#define MARGIN 0.3f
#define BIG 10000.0f

// ---------------------------------------------------------------------------
// Workspace layout (floats):
//   [0, 4096)      sq[i]      row squared norms
//   [4096, 8192)   hard_ap[i] max dist over eq cols      (init 0; dists >= 0)
//   [8192, 12288)  an_g[i]    min dist over gt cols       (init BIG)
//   [12288, 16384) an_l[i]    min dist over lt cols       (init BIG)
//   [16384, 16388) hist[4]    label histogram (int)
//   [16388]        loss_sum   (float)
//   [16389]        cnt_sum    (int)
// ---------------------------------------------------------------------------

__device__ inline void atomicMaxFloatPos(float* addr, float v) {
    atomicMax((int*)addr, __float_as_int(v));   // valid: all values >= 0
}
__device__ inline void atomicMinFloatPos(float* addr, float v) {
    atomicMin((int*)addr, __float_as_int(v));   // valid: all values >= 0
}

__global__ __launch_bounds__(256) void init_kernel(float* ap, float* ang, float* anl,
                                                   int* hist, float* loss, int* cnt) {
    int i = blockIdx.x * 256 + threadIdx.x;
    if (i < N) { ap[i] = 0.0f; ang[i] = BIG; anl[i] = BIG; }
    if (i < 4) hist[i] = 0;
    if (i == 0) { *loss = 0.0f; *cnt = 0; }
}

// One wave (64 lanes) per row: sq[i] = sum_k x[i,k]^2; lane 0 builds histogram.
__global__ __launch_bounds__(256) void sq_hist_kernel(const float* __restrict__ x,
                                                      const int* __restrict__ tgt,
                                                      float* __restrict__ sq, int* hist) {
    int wave = threadIdx.x >> 6, lane = threadIdx.x & 63;
    int row = blockIdx.x * 4 + wave;
    const float4 v = *(const float4*)(x + (size_t)row * D + lane * 4);
    float s = v.x * v.x + v.y * v.y + v.z * v.z + v.w * v.w;
    #pragma unroll
    for (int off = 32; off; off >>= 1) s += __shfl_down(s, off);
    if (lane == 0) {
        sq[row] = s;
        atomicAdd(&hist[tgt[row] & 3], 1);
    }
}

// 64x64 output tile per 256-thread block; each thread owns a 4x4 micro-tile.
// Fused: dist computation + dist write + per-row eq-max / gt-min / lt-min.
__global__ __launch_bounds__(256) void dist_kernel(const float* __restrict__ x,
                                                   const int* __restrict__ tgt,
                                                   const float* __restrict__ sq,
                                                   float* __restrict__ dist,
                                                   float* ap, float* ang, float* anl) {
    constexpr int BM = 64, BN = 64, BK = 16;
    __shared__ float As[BK][BM];
    __shared__ float Bs[BK][BN];

    const int t  = threadIdx.x;
    const int tx = t & 15;        // column group 0..15  (4 cols each)
    const int ty = t >> 4;        // row group    0..15  (4 rows each)
    const int row0 = blockIdx.y * BM;
    const int col0 = blockIdx.x * BN;

    // Staging assignment: thread t loads float4 at (m = t/4, k = (t%4)*4).
    const int lm = t >> 2;
    const int lk = (t & 3) * 4;
    const float* arow = x + (size_t)(row0 + lm) * D + lk;
    const float* brow = x + (size_t)(col0 + lm) * D + lk;

    float acc[4][4] = {};

    for (int k0 = 0; k0 < D; k0 += BK) {
        float4 av = *(const float4*)(arow + k0);
        float4 bv = *(const float4*)(brow + k0);
        __syncthreads();   // previous iteration's reads done before overwrite
        As[lk + 0][lm] = av.x; As[lk + 1][lm] = av.y;
        As[lk + 2][lm] = av.z; As[lk + 3][lm] = av.w;
        Bs[lk + 0][lm] = bv.x; Bs[lk + 1][lm] = bv.y;
        Bs[lk + 2][lm] = bv.z; Bs[lk + 3][lm] = bv.w;
        __syncthreads();
        #pragma unroll
        for (int kk = 0; kk < BK; ++kk) {
            const float4 a = *(const float4*)&As[kk][ty * 4];
            const float4 b = *(const float4*)&Bs[kk][tx * 4];
            acc[0][0] += a.x * b.x; acc[0][1] += a.x * b.y; acc[0][2] += a.x * b.z; acc[0][3] += a.x * b.w;
            acc[1][0] += a.y * b.x; acc[1][1] += a.y * b.y; acc[1][2] += a.y * b.z; acc[1][3] += a.y * b.w;
            acc[2][0] += a.z * b.x; acc[2][1] += a.z * b.y; acc[2][2] += a.z * b.z; acc[2][3] += a.z * b.w;
            acc[3][0] += a.w * b.x; acc[3][1] += a.w * b.y; acc[3][2] += a.w * b.z; acc[3][3] += a.w * b.w;
        }
    }

    // Epilogue: dist, write, per-row masked reductions.
    const int gi_base = row0 + ty * 4;
    const int gj_base = col0 + tx * 4;
    int   tj[4];
    float sqj[4];
    #pragma unroll
    for (int jn = 0; jn < 4; ++jn) {
        tj[jn]  = tgt[gj_base + jn];
        sqj[jn] = sq[gj_base + jn];
    }

    #pragma unroll
    for (int im = 0; im < 4; ++im) {
        const int   gi   = gi_base + im;
        const float sqi  = sq[gi];
        const int   ti   = tgt[gi];
        float mx = 0.0f, mg = BIG, ml = BIG;
        float4 o;
        float dv[4];
        #pragma unroll
        for (int jn = 0; jn < 4; ++jn) {
            float d2 = sqi + sqj[jn] - 2.0f * acc[im][jn];
            dv[jn] = sqrtf(fmaxf(d2, 0.0f));
            if (tj[jn] == ti)      mx = fmaxf(mx, dv[jn]);
            else if (tj[jn] > ti)  mg = fminf(mg, dv[jn]);
            else                   ml = fminf(ml, dv[jn]);
        }
        o.x = dv[0]; o.y = dv[1]; o.z = dv[2]; o.w = dv[3];
        *(float4*)(dist + (size_t)gi * N + gj_base) = o;

        // Reduce across the 16 column-threads of this row group (lanes tx=0..15
        // are contiguous within the wave, so xor-shuffles 1,2,4,8 stay inside).
        #pragma unroll
        for (int off = 1; off < 16; off <<= 1) {
            mx = fmaxf(mx, __shfl_xor(mx, off));
            mg = fminf(mg, __shfl_xor(mg, off));
            ml = fminf(ml, __shfl_xor(ml, off));
        }
        if (tx == 0) {
            atomicMaxFloatPos(&ap[gi], mx);
            atomicMinFloatPos(&ang[gi], mg);
            atomicMinFloatPos(&anl[gi], ml);
        }
    }
}

__global__ __launch_bounds__(256) void finish_kernel(const float* __restrict__ ap,
                                                     const float* __restrict__ ang,
                                                     const float* __restrict__ anl,
                                                     const int* __restrict__ tgt,
                                                     const int* __restrict__ hist,
                                                     float* loss_acc, int* cnt_acc) {
    int i = blockIdx.x * 256 + threadIdx.x;
    float term = 0.0f; int c = 0;
    if (i < N) {
        term = fmaxf(ap[i] - fabsf(ang[i] - anl[i]) + MARGIN, 0.0f);
        c = (hist[tgt[i] & 3] == 1) ? 1 : 0;
    }
    #pragma unroll
    for (int off = 32; off; off >>= 1) {
        term += __shfl_down(term, off);
        c    += __shfl_down(c, off);
    }
    if ((threadIdx.x & 63) == 0) {
        atomicAdd(loss_acc, term);
        atomicAdd(cnt_acc, c);
    }
}

__global__ void write_kernel(const float* loss_acc, const int* cnt_acc, float* out) {
    out[0] = loss_acc[0] * (1.0f / N);
    out[1 + (size_t)N * N] = (float)cnt_acc[0];
}

extern "C" void kernel_launch(void* const* d_in, const int* in_sizes, int n_in,
                              void* d_out, int out_size, void* d_ws, size_t ws_size,
                              hipStream_t stream) {
    const float* x   = (const float*)d_in[0];
    const int*   tgt = (const int*)d_in[1];
    float* out = (float*)d_out;
    float* ws  = (float*)d_ws;

    float* sq   = ws;
    float* ap   = ws + 4096;
    float* ang  = ws + 8192;
    float* anl  = ws + 12288;
    int*   hist = (int*)(ws + 16384);
    float* loss = ws + 16388;
    int*   cnt  = (int*)(ws + 16389);

    init_kernel<<<16, 256, 0, stream>>>(ap, ang, anl, hist, loss, cnt);
    sq_hist_kernel<<<N / 4, 256, 0, stream>>>(x, tgt, sq, hist);
    dim3 grid(N / 64, N / 64);
    dist_kernel<<<grid, 256, 0, stream>>>(x, tgt, sq, out + 1, ap, ang, anl);
    finish_kernel<<<16, 256, 0, stream>>>(ap, ang, anl, tgt, hist, loss, cnt);
    write_kernel<<<1, 1, 0, stream>>>(loss, cnt, out);
}

// Round 3
// 210.097 us; speedup vs baseline: 1.2584x; 1.2584x over previous
//
#include <hip/hip_runtime.h>

#define N 4096
#define D 256
#define MARGIN 0.3f
#define BIG 10000.0f

typedef __bf16  bf16x8   __attribute__((ext_vector_type(8)));
typedef float   floatx16 __attribute__((ext_vector_type(16)));

__device__ inline unsigned short f2bf(float f) {      // RNE fp32 -> bf16
    unsigned u = __float_as_uint(f);
    u += 0x7FFF + ((u >> 16) & 1);
    return (unsigned short)(u >> 16);
}
__device__ inline float bf2f(unsigned short h) {
    return __uint_as_float(((unsigned)h) << 16);
}

__device__ inline void atomicMaxFloatPos(float* addr, float v) {
    atomicMax((int*)addr, __float_as_int(v));   // valid: all values >= 0
}
__device__ inline void atomicMinFloatPos(float* addr, float v) {
    atomicMin((int*)addr, __float_as_int(v));
}

__global__ __launch_bounds__(256) void init_kernel(float* ap, float* ang, float* anl,
                                                   int* hist, float* loss, int* cnt) {
    int i = blockIdx.x * 256 + threadIdx.x;
    if (i < N) { ap[i] = 0.0f; ang[i] = BIG; anl[i] = BIG; }
    if (i < 4) hist[i] = 0;
    if (i == 0) { *loss = 0.0f; *cnt = 0; }
}

// One wave per row: sq[i] = sum_k x[i,k]^2; lane 0 builds label histogram.
__global__ __launch_bounds__(256) void sq_hist_kernel(const float* __restrict__ x,
                                                      const int* __restrict__ tgt,
                                                      float* __restrict__ sq, int* hist) {
    int wave = threadIdx.x >> 6, lane = threadIdx.x & 63;
    int row = blockIdx.x * 4 + wave;
    const float4 v = *(const float4*)(x + (size_t)row * D + lane * 4);
    float s = v.x * v.x + v.y * v.y + v.z * v.z + v.w * v.w;
    #pragma unroll
    for (int off = 32; off; off >>= 1) s += __shfl_down(s, off);
    if (lane == 0) {
        sq[row] = s;
        atomicAdd(&hist[tgt[row] & 3], 1);
    }
}

// 128x128 tile per 256-thread block. Split-bf16 MFMA: x = hi + lo,
// dot ~= hi*hi + hi*lo + lo*hi  (3x v_mfma_f32_32x32x16_bf16).
// 4 waves in 2x2; each wave owns a 64x64 region = 2x2 MFMA tiles of 32x32.
// BK=32, LDS stride 40 ushorts (80 B) -> total LDS 40 KiB (< 64 KiB cap).
__global__ __launch_bounds__(256) void dist_kernel(const float* __restrict__ x,
                                                   const int* __restrict__ tgt,
                                                   const float* __restrict__ sq,
                                                   float* __restrict__ dist,
                                                   float* ap, float* ang, float* anl) {
    constexpr int BK = 32;
    constexpr int LS = 40;                 // padded LDS stride in ushorts
    __shared__ unsigned short Ah[128][LS], Al[128][LS];
    __shared__ unsigned short Bh[128][LS], Bl[128][LS];

    const int t    = threadIdx.x;
    const int wave = t >> 6, lane = t & 63;
    const int wm   = (wave >> 1) * 64;     // wave row offset in tile
    const int wn   = (wave & 1) * 64;      // wave col offset in tile
    const int row0 = blockIdx.y * 128;
    const int col0 = blockIdx.x * 128;

    floatx16 acc[2][2];
    #pragma unroll
    for (int mt = 0; mt < 2; ++mt)
        #pragma unroll
        for (int nt = 0; nt < 2; ++nt)
            #pragma unroll
            for (int r = 0; r < 16; ++r) acc[mt][nt][r] = 0.0f;

    const int ar = lane & 31;              // fragment row within 32-tile
    const int kh = (lane >> 5) * 8;        // k-half offset within K=16 step

    for (int k0 = 0; k0 < D; k0 += BK) {
        __syncthreads();                   // previous stage's reads complete
        #pragma unroll
        for (int it = 0; it < 4; ++it) {
            int idx = it * 256 + t;
            int r   = idx >> 3;            // 0..127
            int kq  = (idx & 7) * 4;       // 0..28
            float4 va = *(const float4*)(x + (size_t)(row0 + r) * D + k0 + kq);
            float4 vb = *(const float4*)(x + (size_t)(col0 + r) * D + k0 + kq);
            ushort4 h, l;
            float hf;
            h.x = f2bf(va.x); hf = bf2f(h.x); l.x = f2bf(va.x - hf);
            h.y = f2bf(va.y); hf = bf2f(h.y); l.y = f2bf(va.y - hf);
            h.z = f2bf(va.z); hf = bf2f(h.z); l.z = f2bf(va.z - hf);
            h.w = f2bf(va.w); hf = bf2f(h.w); l.w = f2bf(va.w - hf);
            *(ushort4*)&Ah[r][kq] = h;
            *(ushort4*)&Al[r][kq] = l;
            h.x = f2bf(vb.x); hf = bf2f(h.x); l.x = f2bf(vb.x - hf);
            h.y = f2bf(vb.y); hf = bf2f(h.y); l.y = f2bf(vb.y - hf);
            h.z = f2bf(vb.z); hf = bf2f(h.z); l.z = f2bf(vb.z - hf);
            h.w = f2bf(vb.w); hf = bf2f(h.w); l.w = f2bf(vb.w - hf);
            *(ushort4*)&Bh[r][kq] = h;
            *(ushort4*)&Bl[r][kq] = l;
        }
        __syncthreads();

        #pragma unroll
        for (int kk = 0; kk < BK; kk += 16) {
            const int kb = kk + kh;
            bf16x8 a0h = *(bf16x8*)&Ah[wm      + ar][kb];
            bf16x8 a0l = *(bf16x8*)&Al[wm      + ar][kb];
            bf16x8 a1h = *(bf16x8*)&Ah[wm + 32 + ar][kb];
            bf16x8 a1l = *(bf16x8*)&Al[wm + 32 + ar][kb];
            bf16x8 b0h = *(bf16x8*)&Bh[wn      + ar][kb];
            bf16x8 b0l = *(bf16x8*)&Bl[wn      + ar][kb];
            bf16x8 b1h = *(bf16x8*)&Bh[wn + 32 + ar][kb];
            bf16x8 b1l = *(bf16x8*)&Bl[wn + 32 + ar][kb];

            acc[0][0] = __builtin_amdgcn_mfma_f32_32x32x16_bf16(a0h, b0h, acc[0][0], 0, 0, 0);
            acc[0][0] = __builtin_amdgcn_mfma_f32_32x32x16_bf16(a0h, b0l, acc[0][0], 0, 0, 0);
            acc[0][0] = __builtin_amdgcn_mfma_f32_32x32x16_bf16(a0l, b0h, acc[0][0], 0, 0, 0);

            acc[0][1] = __builtin_amdgcn_mfma_f32_32x32x16_bf16(a0h, b1h, acc[0][1], 0, 0, 0);
            acc[0][1] = __builtin_amdgcn_mfma_f32_32x32x16_bf16(a0h, b1l, acc[0][1], 0, 0, 0);
            acc[0][1] = __builtin_amdgcn_mfma_f32_32x32x16_bf16(a0l, b1h, acc[0][1], 0, 0, 0);

            acc[1][0] = __builtin_amdgcn_mfma_f32_32x32x16_bf16(a1h, b0h, acc[1][0], 0, 0, 0);
            acc[1][0] = __builtin_amdgcn_mfma_f32_32x32x16_bf16(a1h, b0l, acc[1][0], 0, 0, 0);
            acc[1][0] = __builtin_amdgcn_mfma_f32_32x32x16_bf16(a1l, b0h, acc[1][0], 0, 0, 0);

            acc[1][1] = __builtin_amdgcn_mfma_f32_32x32x16_bf16(a1h, b1h, acc[1][1], 0, 0, 0);
            acc[1][1] = __builtin_amdgcn_mfma_f32_32x32x16_bf16(a1h, b1l, acc[1][1], 0, 0, 0);
            acc[1][1] = __builtin_amdgcn_mfma_f32_32x32x16_bf16(a1l, b1h, acc[1][1], 0, 0, 0);
        }
    }

    // Epilogue. C/D layout (verified m74/m101): col = lane&31,
    // row = (r&3) + 8*(r>>2) + 4*(lane>>5).
    int   gcol[2], tc[2];
    float sqc[2];
    #pragma unroll
    for (int nt = 0; nt < 2; ++nt) {
        gcol[nt] = col0 + wn + nt * 32 + (lane & 31);
        sqc[nt]  = sq[gcol[nt]];
        tc[nt]   = tgt[gcol[nt]];
    }
    const int rl_base = 4 * (lane >> 5);

    #pragma unroll
    for (int mt = 0; mt < 2; ++mt) {
        #pragma unroll
        for (int r = 0; r < 16; ++r) {
            const int row_local = (r & 3) + 8 * (r >> 2) + rl_base;
            const int grow = row0 + wm + mt * 32 + row_local;
            const float sqi = sq[grow];
            const int   ti  = tgt[grow];
            float mx = 0.0f, mg = BIG, ml = BIG;
            #pragma unroll
            for (int nt = 0; nt < 2; ++nt) {
                float d2 = sqi + sqc[nt] - 2.0f * acc[mt][nt][r];
                float dv = sqrtf(fmaxf(d2, 0.0f));
                dist[(size_t)grow * N + gcol[nt]] = dv;
                if (tc[nt] == ti)      mx = fmaxf(mx, dv);
                else if (tc[nt] > ti)  mg = fminf(mg, dv);
                else                   ml = fminf(ml, dv);
            }
            #pragma unroll
            for (int off = 1; off < 32; off <<= 1) {
                mx = fmaxf(mx, __shfl_xor(mx, off));
                mg = fminf(mg, __shfl_xor(mg, off));
                ml = fminf(ml, __shfl_xor(ml, off));
            }
            if ((lane & 31) == 0) {
                atomicMaxFloatPos(&ap[grow], mx);
                atomicMinFloatPos(&ang[grow], mg);
                atomicMinFloatPos(&anl[grow], ml);
            }
        }
    }
}

__global__ __launch_bounds__(256) void finish_kernel(const float* __restrict__ ap,
                                                     const float* __restrict__ ang,
                                                     const float* __restrict__ anl,
                                                     const int* __restrict__ tgt,
                                                     const int* __restrict__ hist,
                                                     float* loss_acc, int* cnt_acc) {
    int i = blockIdx.x * 256 + threadIdx.x;
    float term = 0.0f; int c = 0;
    if (i < N) {
        term = fmaxf(ap[i] - fabsf(ang[i] - anl[i]) + MARGIN, 0.0f);
        c = (hist[tgt[i] & 3] == 1) ? 1 : 0;
    }
    #pragma unroll
    for (int off = 32; off; off >>= 1) {
        term += __shfl_down(term, off);
        c    += __shfl_down(c, off);
    }
    if ((threadIdx.x & 63) == 0) {
        atomicAdd(loss_acc, term);
        atomicAdd(cnt_acc, c);
    }
}

__global__ void write_kernel(const float* loss_acc, const int* cnt_acc, float* out) {
    out[0] = loss_acc[0] * (1.0f / N);
    out[1 + (size_t)N * N] = (float)cnt_acc[0];
}

extern "C" void kernel_launch(void* const* d_in, const int* in_sizes, int n_in,
                              void* d_out, int out_size, void* d_ws, size_t ws_size,
                              hipStream_t stream) {
    const float* x   = (const float*)d_in[0];
    const int*   tgt = (const int*)d_in[1];
    float* out = (float*)d_out;
    float* ws  = (float*)d_ws;

    float* sq   = ws;
    float* ap   = ws + 4096;
    float* ang  = ws + 8192;
    float* anl  = ws + 12288;
    int*   hist = (int*)(ws + 16384);
    float* loss = ws + 16388;
    int*   cnt  = (int*)(ws + 16389);

    init_kernel<<<16, 256, 0, stream>>>(ap, ang, anl, hist, loss, cnt);
    sq_hist_kernel<<<N / 4, 256, 0, stream>>>(x, tgt, sq, hist);
    dim3 grid(N / 128, N / 128);
    dist_kernel<<<grid, 256, 0, stream>>>(x, tgt, sq, out + 1, ap, ang, anl);
    finish_kernel<<<16, 256, 0, stream>>>(ap, ang, anl, tgt, hist, loss, cnt);
    write_kernel<<<1, 1, 0, stream>>>(loss, cnt, out);
}